// Round 13
// baseline (93.347 us; speedup 1.0000x reference)
//
#include <hip/hip_runtime.h>
#include <stdint.h>

typedef __attribute__((ext_vector_type(8))) short bf16x8;
typedef __attribute__((ext_vector_type(4))) float f32x4;

#define MFMA16(a, b, c) __builtin_amdgcn_mfma_f32_16x16x32_bf16((a), (b), (c), 0, 0, 0)

__device__ __forceinline__ void gload_lds16(const void* g, void* l) {
  __builtin_amdgcn_global_load_lds((const __attribute__((address_space(1))) void*)g,
                                   (__attribute__((address_space(3))) void*)l,
                                   16, 0, 0);
}

static __device__ __forceinline__ unsigned f2bf(float f) {
  union { float f; unsigned u; } cv;
  cv.f = f;
  return (cv.u + 0x7fffu + ((cv.u >> 16) & 1u)) >> 16;
}

#define BATCH 8192
#define ROWD  2128
#define HID   512
#define LATD  256
#define KC1   272            // 8-elem k-chunks (272*8 = 2176, zero-padded)
#define NT2   34             // 64-k tiles (34*64 = 2176)
#define HSL_TW (BATCH * HID) // ushorts per tower in h_sl

// LDS partition (ushort offsets): A = 2 x [128][72], B = 2 x [8][256][8]
#define A_BUF 9216
#define B_OFF (2 * A_BUF)
#define B_BUF 16384
#define LDS_BYTES ((B_OFF + 2 * B_BUF) * 2)   // 102,400 B

// ---------- prep: k-chunked transpose-cast ----------
__global__ __launch_bounds__(256) void ASAECF_tcast(
    const float* __restrict__ in0, const float* __restrict__ in1,
    unsigned short* __restrict__ out, int N, int lgN, int Kin, int KC, int perm)
{
  const float* __restrict__ in = blockIdx.z ? in1 : in0;
  unsigned short* __restrict__ o = out + (size_t)blockIdx.z * KC * N * 8;
  const int s = blockIdx.x * 256 + threadIdx.x;   // slot index
  const int kc = s >> lgN, n = s & (N - 1);
  unsigned short v[8];
#pragma unroll
  for (int e = 0; e < 8; ++e) {
    const int k = kc * 8 + e;
    float f = 0.0f;
    if (k < Kin) {
      const int src = perm ? (k < 128 ? k + 2000 : k - 128) : k;
      f = in[(size_t)src * N + n];
    }
    v[e] = (unsigned short)f2bf(f);
  }
  *(uint4*)(o + (size_t)s * 8) = *(const uint4*)v;
}

// ---------- GEMM1: h = relu(gather(look) @ W1p + b1) ----------
// BM=128, BN=256 (nh half), BK=64. 512 thr = 8 waves (2M x 4N), wave 64x64.
// Grid = 64 mb x 2 nh x 2 towers = 256 (1 block/CU).
// m97 recipe: B staged via global_load_lds width-16 into double-buffered LDS
// (read once per wave as ds_read_b128); A gather issue-early/write-late reg
// pipeline -> LDS. 32 MFMA per wave between barriers (34 barriers total).
// Epilogue: LDS-transpose so h is written as 128-B contiguous b128 stores.
__global__ __launch_bounds__(512) void ASAECF_gemm1(
    const int* __restrict__ x,
    const float* __restrict__ ulook, const float* __restrict__ ilook,
    const unsigned short* __restrict__ w1s,   // [2][KC1][512][8]
    const float* __restrict__ ub1, const float* __restrict__ ib1,
    unsigned short* __restrict__ hsl)         // [2][chunk64][kc][row64][8]
{
  extern __shared__ unsigned short LDS[];

  const int bid   = blockIdx.x;             // 0..255
  const int xcd   = bid & 7;
  const int idx   = bid >> 3;               // 0..31
  const int tower = xcd >> 2;
  const int nh    = idx & 1;                // nh pair adjacent on same XCD
  const int mb    = (xcd & 3) * 16 + (idx >> 1);   // 0..63

  const float* __restrict__ look = tower ? ilook : ulook;
  const unsigned short* __restrict__ w1 = w1s + (size_t)tower * KC1 * HID * 8;
  const float* __restrict__ b1 = tower ? ib1 : ub1;
  unsigned short* __restrict__ hout = hsl + (size_t)tower * HSL_TW;

  const int tid  = threadIdx.x;
  const int lane = tid & 63, wid = tid >> 6;
  const int wm   = wid >> 2, wn = wid & 3;    // wave tile: rows wm*64, cols wn*64
  const int fr   = lane & 15, fq = lane >> 4;
  const int row0 = mb * 128;

  // A staging: thread -> (row ar, 16 consecutive k at q16)
  const int ar  = tid >> 2;                  // 0..127
  const int q16 = (tid & 3) * 16;            // 0,16,32,48
  const long long abase = (long long)x[(row0 + ar) * 2 + tower] * ROWD;

  f32x4 rA[4];
  auto loadA = [&](int t) {
    const int kb = t * 64 + q16;
#pragma unroll
    for (int i = 0; i < 4; ++i) {
      rA[i] = f32x4{0.0f, 0.0f, 0.0f, 0.0f};
      if (kb + i * 4 + 4 <= ROWD)
        rA[i] = *(const f32x4*)(look + abase + kb + i * 4);
    }
  };
  auto writeA = [&](int buf) {
    unsigned short v[16];
#pragma unroll
    for (int i = 0; i < 4; ++i)
#pragma unroll
      for (int e = 0; e < 4; ++e)
        v[i * 4 + e] = (unsigned short)f2bf(rA[i][e]);
    unsigned short* d = &LDS[buf * A_BUF + ar * 72 + q16];
    *(bf16x8*)d = *(const bf16x8*)v;
    *(bf16x8*)(d + 8) = *(const bf16x8*)(v + 8);
  };
  auto stageB = [&](int t, int buf) {
    // wave wid owns kc-slab wid of this tile; 4 x 64-col groups
    unsigned short* bd = &LDS[B_OFF + buf * B_BUF + wid * 256 * 8];
    const unsigned short* gs = w1 + ((size_t)(t * 8 + wid) * 512 + nh * 256) * 8;
#pragma unroll
    for (int cg = 0; cg < 4; ++cg)
      gload_lds16(gs + (cg * 64 + lane) * 8, bd + cg * 64 * 8);
  };

  f32x4 acc[4][4] = {};

  // prologue: tile 0 fully staged
  loadA(0);
  stageB(0, 0);
  writeA(0);
  __syncthreads();

  int buf = 0;
  for (int t = 0; t < NT2; ++t) {
    const bool pre = (t + 1 < NT2);
    if (pre) { stageB(t + 1, buf ^ 1); loadA(t + 1); }   // issue-early

    // compute on buf: 2 sub-tiles of K=32, 32 MFMA/wave
#pragma unroll
    for (int ks = 0; ks < 2; ++ks) {
      bf16x8 af[4], bg[4];
#pragma unroll
      for (int m = 0; m < 4; ++m)
        af[m] = *(const bf16x8*)&LDS[buf * A_BUF + (wm * 64 + m * 16 + fr) * 72 + ks * 32 + fq * 8];
#pragma unroll
      for (int n = 0; n < 4; ++n)
        bg[n] = *(const bf16x8*)&LDS[B_OFF + buf * B_BUF + (((ks * 4 + fq) * 256) + wn * 64 + n * 16 + fr) * 8];
#pragma unroll
      for (int n = 0; n < 4; ++n)
#pragma unroll
        for (int m = 0; m < 4; ++m)
          acc[m][n] = MFMA16(af[m], bg[n], acc[m][n]);
    }

    if (pre) writeA(buf ^ 1);                            // write-late
    __syncthreads();                                     // staged tile ready
    buf ^= 1;
  }

  // ---- epilogue: bias+relu, LDS transpose, contiguous b128 h stores ----
  unsigned short* W = &LDS[wid * 64 * 72];               // per-wave 64x72 region
#pragma unroll
  for (int n = 0; n < 4; ++n) {
    const int col_l = n * 16 + fr;                       // 0..63 within wave
    const float bb = b1[nh * 256 + wn * 64 + col_l];
#pragma unroll
    for (int m = 0; m < 4; ++m)
#pragma unroll
      for (int i = 0; i < 4; ++i) {
        const int row_l = m * 16 + fq * 4 + i;           // 0..63
        const float v = fmaxf(acc[m][n][i] + bb, 0.0f);
        W[row_l * 72 + col_l] = (unsigned short)f2bf(v);
      }
  }
  __syncthreads();
  {
    const int g  = lane >> 3;                            // kc-slot 0..7 within wave cols
    const int ri = lane & 7;
    const int kc = (nh * 256 + wn * 64 + g * 8) >> 3;    // global kc
    const int chunk = mb * 2 + wm;
    unsigned short* hb = hout + ((size_t)(chunk * 64 + kc) * 64) * 8;
#pragma unroll
    for (int rr = 0; rr < 8; ++rr) {
      const int row_l = rr * 8 + ri;
      bf16x8 val = *(const bf16x8*)&W[row_l * 72 + g * 8];
      *(bf16x8*)&hb[row_l * 8] = val;
    }
  }
}

// ---------- GEMM2 + dot, fully fused, no LDS staging ----------
__global__ __launch_bounds__(512, 2) void ASAECF_gemm2dot(
    const unsigned short* __restrict__ hsl,   // [2][chunk64][kc][row64][8]
    const unsigned short* __restrict__ w2s,   // [2][64][256][8]
    const float* __restrict__ ub2, const float* __restrict__ ib2,
    float* __restrict__ out)
{
  const int tid  = threadIdx.x;
  const int lane = tid & 63, wid = tid >> 6;
  const int fr   = lane & 15, fq = lane >> 4;
  const int rb   = blockIdx.x;          // 32-row block
  const int row0 = rb * 32;

  const unsigned short* __restrict__ hu = hsl;
  const unsigned short* __restrict__ hv = hsl + (size_t)HSL_TW;
  const size_t abase = ((size_t)(rb >> 1) * 64) * 64 * 8;
  const int lrow0 = (rb & 1) * 32;

  f32x4 au[2][2] = {}, av[2][2] = {};

#pragma unroll
  for (int t = 0; t < 8; ++t) {
#pragma unroll
    for (int s = 0; s < 2; ++s) {
      const int kc = t * 8 + s * 4 + fq;
      bf16x8 a_u[2], a_v[2], b_u[2], b_v[2];
#pragma unroll
      for (int m = 0; m < 2; ++m) {
        const size_t off = abase + ((size_t)kc * 64 + lrow0 + m * 16 + fr) * 8;
        a_u[m] = *(const bf16x8*)(hu + off);
        a_v[m] = *(const bf16x8*)(hv + off);
      }
#pragma unroll
      for (int n = 0; n < 2; ++n) {
        const int col = wid * 32 + n * 16 + fr;
        const size_t offb = ((size_t)kc * 256 + col) * 8;
        b_u[n] = *(const bf16x8*)(w2s + offb);
        b_v[n] = *(const bf16x8*)(w2s + (size_t)64 * 256 * 8 + offb);
      }
#pragma unroll
      for (int m = 0; m < 2; ++m)
#pragma unroll
        for (int n = 0; n < 2; ++n) {
          au[m][n] = MFMA16(a_u[m], b_u[n], au[m][n]);
          av[m][n] = MFMA16(a_v[m], b_v[n], av[m][n]);
        }
    }
  }

  // bias + per-row dot + reduction
  __shared__ float red[8][32];
  float bu[2], bv[2];
#pragma unroll
  for (int n = 0; n < 2; ++n) {
    const int col = wid * 32 + n * 16 + fr;
    bu[n] = ub2[col];
    bv[n] = ib2[col];
  }
#pragma unroll
  for (int m = 0; m < 2; ++m)
#pragma unroll
    for (int i = 0; i < 4; ++i) {
      float p = 0.0f;
#pragma unroll
      for (int n = 0; n < 2; ++n)
        p += (au[m][n][i] + bu[n]) * (av[m][n][i] + bv[n]);
      p += __shfl_xor(p, 1, 64);
      p += __shfl_xor(p, 2, 64);
      p += __shfl_xor(p, 4, 64);
      p += __shfl_xor(p, 8, 64);
      if (fr == 0) red[wid][m * 16 + fq * 4 + i] = p;
    }
  __syncthreads();
  if (tid < 32) {
    float s = 0.0f;
#pragma unroll
    for (int w = 0; w < 8; ++w) s += red[w][tid];
    out[row0 + tid] = s;
  }
}

extern "C" void kernel_launch(void* const* d_in, const int* in_sizes, int n_in,
                              void* d_out, int out_size, void* d_ws, size_t ws_size,
                              hipStream_t stream) {
  (void)in_sizes; (void)n_in; (void)out_size; (void)ws_size;
  const int*   x     = (const int*)d_in[0];
  const float* ulook = (const float*)d_in[1];
  const float* ilook = (const float*)d_in[2];
  const float* uW1   = (const float*)d_in[3];
  const float* ub1   = (const float*)d_in[4];
  const float* uW2   = (const float*)d_in[5];
  const float* ub2   = (const float*)d_in[6];
  const float* iW1   = (const float*)d_in[7];
  const float* ib1   = (const float*)d_in[8];
  const float* iW2   = (const float*)d_in[9];
  const float* ib2   = (const float*)d_in[10];
  float* out = (float*)d_out;

  // workspace layout (bytes):
  //   w1s: [2][272][512][8] bf16 = 4,456,448
  //   w2s: [2][64][256][8]  bf16 =   524,288  @ 4,456,448
  //   hsl: [2][8192*512]    bf16 = 16,777,216 @ 4,980,736
  char* ws = (char*)d_ws;
  unsigned short* w1s = (unsigned short*)(ws);
  unsigned short* w2s = (unsigned short*)(ws + 4456448);
  unsigned short* hsl = (unsigned short*)(ws + 4980736);

  ASAECF_tcast<<<dim3(544, 1, 2), 256, 0, stream>>>(uW1, iW1, w1s, 512, 9, ROWD, KC1, 1);
  ASAECF_tcast<<<dim3(64, 1, 2),  256, 0, stream>>>(uW2, iW2, w2s, 256, 8, HID, 64, 0);
  ASAECF_gemm1<<<dim3(256), 512, LDS_BYTES, stream>>>(x, ulook, ilook, w1s, ub1, ib1, hsl);
  ASAECF_gemm2dot<<<dim3(256), 512, 0, stream>>>(hsl, w2s, ub2, ib2, out);
}

// Round 14
// 77.467 us; speedup vs baseline: 1.2050x; 1.2050x over previous
//
#include <hip/hip_runtime.h>
#include <stdint.h>

typedef __attribute__((ext_vector_type(8))) short bf16x8;
typedef __attribute__((ext_vector_type(4))) float f32x4;

#define MFMA16(a, b, c) __builtin_amdgcn_mfma_f32_16x16x32_bf16((a), (b), (c), 0, 0, 0)

static __device__ __forceinline__ unsigned f2bf(float f) {
  union { float f; unsigned u; } cv;
  cv.f = f;
  return (cv.u + 0x7fffu + ((cv.u >> 16) & 1u)) >> 16;
}

#define BATCH 8192
#define ROWD  2128
#define HID   512
#define LATD  256
#define KC1   272            // 8-elem k-chunks for layer 1 (272*8 = 2176, zero-padded)
#define NT1   68             // 32-k tiles (68*32 = 2176; trailing tiles zero-padded)
#define HSL_TW (BATCH * HID) // ushorts per tower in h_sl

// ---------- prep: k-chunked transpose-cast (both weight mats, one launch) ----------
__device__ __forceinline__ void tcast_body(
    const float* __restrict__ in, unsigned short* __restrict__ o,
    int s, int N, int lgN, int Kin, int perm)
{
  const int kc = s >> lgN, n = s & (N - 1);
  unsigned short v[8];
#pragma unroll
  for (int e = 0; e < 8; ++e) {
    const int k = kc * 8 + e;
    float f = 0.0f;
    if (k < Kin) {
      const int src = perm ? (k < 128 ? k + 2000 : k - 128) : k;
      f = in[(size_t)src * N + n];
    }
    v[e] = (unsigned short)f2bf(f);
  }
  *(uint4*)(o + (size_t)s * 8) = *(const uint4*)v;
}

__global__ __launch_bounds__(256) void ASAECF_tcast(
    const float* __restrict__ uW1, const float* __restrict__ iW1,
    const float* __restrict__ uW2, const float* __restrict__ iW2,
    unsigned short* __restrict__ w1s, unsigned short* __restrict__ w2s)
{
  const int tower = blockIdx.z;
  const int s = blockIdx.x * 256 + threadIdx.x;
  if (blockIdx.y == 0) {
    // W1: [2128->2176 k][512 n], permuted
    tcast_body(tower ? iW1 : uW1, w1s + (size_t)tower * KC1 * HID * 8,
               s, HID, 9, ROWD, 1);
  } else {
    if (blockIdx.x >= 64) return;
    // W2: [512 k][256 n]
    tcast_body(tower ? iW2 : uW2, w2s + (size_t)tower * 64 * LATD * 8,
               s, LATD, 8, HID, 0);
  }
}

// ---------- GEMM1: h = relu(gather(look) @ W1p + b1) ----------
// BM=128, BN=256 (nh half), BK=32. 512 thr = 8 waves. SINGLE CHANGE vs R9:
// wave tile 64x64 -> 128x32 (af[8], bg[2]): every wave covers all 128 rows
// and a DISTINCT 32-col slice, so B fragments are read once per block
// (1.1 MB vs 2.2 MB; chip 285 -> 143 MB L2 traffic).
// Grid = 64 mb x 2 nh x 2 towers = 256 blocks (1/CU), nh pair on same XCD.
__global__ __launch_bounds__(512) void ASAECF_gemm1(
    const int* __restrict__ x,
    const float* __restrict__ ulook, const float* __restrict__ ilook,
    const unsigned short* __restrict__ w1s,   // [2][KC1][512][8]
    const float* __restrict__ ub1, const float* __restrict__ ib1,
    unsigned short* __restrict__ hsl)         // [2][chunk64][kc][row64][8]
{
  const int bid   = blockIdx.x;             // 0..255
  const int xcd   = bid & 7;
  const int idx   = bid >> 3;               // 0..31
  const int tower = xcd >> 2;
  const int nh    = idx & 1;
  const int mb    = (xcd & 3) * 16 + (idx >> 1);   // 0..63

  const float* __restrict__ look = tower ? ilook : ulook;
  const unsigned short* __restrict__ w1 = w1s + (size_t)tower * KC1 * HID * 8;
  const float* __restrict__ b1 = tower ? ib1 : ub1;
  unsigned short* __restrict__ hout = hsl + (size_t)tower * HSL_TW;

  __shared__ unsigned short Ab[2][128 * 40];  // 128 rows x 32 k, 80-B padded rows

  const int tid  = threadIdx.x;
  const int lane = tid & 63, wid = tid >> 6;  // wid 0..7 -> 32-col slice
  const int fr   = lane & 15, fq = lane >> 4;
  const int row0 = mb * 128;

  // A staging: thread -> (row ar, 4 consecutive k at ak)
  const int ar = tid >> 2, ak = (tid & 3) * 8;       // 128 rows x 8 floats? no:
  // 512 threads, 128 rows -> 4 threads/row, 8 floats each would be 4096... BK=32
  // needs 128*32 = 4096 floats: thread -> 8 floats. ar = tid>>2, ak = (tid&3)*8.
  const long long arow = (long long)x[(row0 + ar) * 2 + tower] * ROWD + ak;

  // B fragment offsets within one k-tile slab (4*512*8 ushorts)
  int boff[2];
#pragma unroll
  for (int n = 0; n < 2; ++n)
    boff[n] = (fq * 512 + nh * 256 + wid * 32 + n * 16 + fr) * 8;

  struct A8 { f32x4 a, b; };
  auto loadA = [&](int tt) -> A8 {
    A8 v;
    v.a = f32x4{0.0f, 0.0f, 0.0f, 0.0f};
    v.b = f32x4{0.0f, 0.0f, 0.0f, 0.0f};
    if (tt * 32 + ak + 8 <= ROWD) {
      v.a = *(const f32x4*)(look + arow + tt * 32);
      v.b = *(const f32x4*)(look + arow + tt * 32 + 4);
    }
    return v;
  };
  auto writeA = [&](int buf, A8 v) {
    uint2 p, q;
    p.x = f2bf(v.a[0]) | (f2bf(v.a[1]) << 16);
    p.y = f2bf(v.a[2]) | (f2bf(v.a[3]) << 16);
    q.x = f2bf(v.b[0]) | (f2bf(v.b[1]) << 16);
    q.y = f2bf(v.b[2]) | (f2bf(v.b[3]) << 16);
    *(uint2*)&Ab[buf][ar * 40 + ak] = p;
    *(uint2*)&Ab[buf][ar * 40 + ak + 4] = q;
  };

  f32x4 acc[8][2] = {};
  bf16x8 bgc[2], bgn[2];
  A8 rA0, rA1;

  // prologue: A(0) -> Ab[0]; A(1),A(2) in flight; B(0) in flight
  writeA(0, loadA(0));
  rA0 = loadA(1);
  rA1 = loadA(2);
#pragma unroll
  for (int n = 0; n < 2; ++n) bgc[n] = *(const bf16x8*)(w1 + boff[n]);

#pragma unroll 2
  for (int t = 0; t < NT1; ++t) {
    __syncthreads();   // Ab[t&1] ready
    const int cu = t & 1;

    // B prefetch for t+1 (stays in flight through this tile's MFMAs)
    const unsigned short* bpn = w1 + (size_t)(t + 1) * (4 * 512 * 8);
#pragma unroll
    for (int n = 0; n < 2; ++n) bgn[n] = *(const bf16x8*)(bpn + boff[n]);

    bf16x8 af[8];
#pragma unroll
    for (int m = 0; m < 8; ++m)
      af[m] = *(const bf16x8*)&Ab[cu][(m * 16 + fr) * 40 + fq * 8];
#pragma unroll
    for (int n = 0; n < 2; ++n)
#pragma unroll
      for (int m = 0; m < 8; ++m)
        acc[m][n] = MFMA16(af[m], bgc[n], acc[m][n]);

    // deferred A write (loaded 2 tiles ago), then refill the pipe
    if (cu == 0) { writeA(1, rA0); rA0 = loadA(t + 3); }
    else         { writeA(0, rA1); rA1 = loadA(t + 3); }

#pragma unroll
    for (int n = 0; n < 2; ++n) bgc[n] = bgn[n];
  }

  // epilogue: bias + relu + store h in k-chunked slot layout
#pragma unroll
  for (int n = 0; n < 2; ++n) {
    const int col = nh * 256 + wid * 32 + n * 16 + fr;
    const int kc = col >> 3, e = col & 7;
    const float bb = b1[col];
#pragma unroll
    for (int m = 0; m < 8; ++m)
#pragma unroll
      for (int i = 0; i < 4; ++i) {
        const int rowib = m * 16 + fq * 4 + i;          // 0..127 within block
        const int chunk = mb * 2 + (rowib >> 6);
        const int row = rowib & 63;
        const float v = fmaxf(acc[m][n][i] + bb, 0.0f);
        hout[(((size_t)chunk * 64 + kc) * 64 + row) * 8 + e] = (unsigned short)f2bf(v);
      }
  }
}

// ---------- GEMM2 + dot, fully fused, no LDS staging ----------
__global__ __launch_bounds__(512, 2) void ASAECF_gemm2dot(
    const unsigned short* __restrict__ hsl,   // [2][chunk64][kc][row64][8]
    const unsigned short* __restrict__ w2s,   // [2][64][256][8]
    const float* __restrict__ ub2, const float* __restrict__ ib2,
    float* __restrict__ out)
{
  const int tid  = threadIdx.x;
  const int lane = tid & 63, wid = tid >> 6;
  const int fr   = lane & 15, fq = lane >> 4;
  const int rb   = blockIdx.x;          // 32-row block
  const int row0 = rb * 32;

  const unsigned short* __restrict__ hu = hsl;
  const unsigned short* __restrict__ hv = hsl + (size_t)HSL_TW;
  const size_t abase = ((size_t)(rb >> 1) * 64) * 64 * 8;
  const int lrow0 = (rb & 1) * 32;

  f32x4 au[2][2] = {}, av[2][2] = {};

#pragma unroll
  for (int t = 0; t < 8; ++t) {
#pragma unroll
    for (int s = 0; s < 2; ++s) {
      const int kc = t * 8 + s * 4 + fq;
      bf16x8 a_u[2], a_v[2], b_u[2], b_v[2];
#pragma unroll
      for (int m = 0; m < 2; ++m) {
        const size_t off = abase + ((size_t)kc * 64 + lrow0 + m * 16 + fr) * 8;
        a_u[m] = *(const bf16x8*)(hu + off);
        a_v[m] = *(const bf16x8*)(hv + off);
      }
#pragma unroll
      for (int n = 0; n < 2; ++n) {
        const int col = wid * 32 + n * 16 + fr;
        const size_t offb = ((size_t)kc * 256 + col) * 8;
        b_u[n] = *(const bf16x8*)(w2s + offb);
        b_v[n] = *(const bf16x8*)(w2s + (size_t)64 * 256 * 8 + offb);
      }
#pragma unroll
      for (int m = 0; m < 2; ++m)
#pragma unroll
        for (int n = 0; n < 2; ++n) {
          au[m][n] = MFMA16(a_u[m], b_u[n], au[m][n]);
          av[m][n] = MFMA16(a_v[m], b_v[n], av[m][n]);
        }
    }
  }

  // bias + per-row dot + reduction
  __shared__ float red[8][32];
  float bu[2], bv[2];
#pragma unroll
  for (int n = 0; n < 2; ++n) {
    const int col = wid * 32 + n * 16 + fr;
    bu[n] = ub2[col];
    bv[n] = ib2[col];
  }
#pragma unroll
  for (int m = 0; m < 2; ++m)
#pragma unroll
    for (int i = 0; i < 4; ++i) {
      float p = 0.0f;
#pragma unroll
      for (int n = 0; n < 2; ++n)
        p += (au[m][n][i] + bu[n]) * (av[m][n][i] + bv[n]);
      p += __shfl_xor(p, 1, 64);
      p += __shfl_xor(p, 2, 64);
      p += __shfl_xor(p, 4, 64);
      p += __shfl_xor(p, 8, 64);
      if (fr == 0) red[wid][m * 16 + fq * 4 + i] = p;
    }
  __syncthreads();
  if (tid < 32) {
    float s = 0.0f;
#pragma unroll
    for (int w = 0; w < 8; ++w) s += red[w][tid];
    out[row0 + tid] = s;
  }
}

extern "C" void kernel_launch(void* const* d_in, const int* in_sizes, int n_in,
                              void* d_out, int out_size, void* d_ws, size_t ws_size,
                              hipStream_t stream) {
  (void)in_sizes; (void)n_in; (void)out_size; (void)ws_size;
  const int*   x     = (const int*)d_in[0];
  const float* ulook = (const float*)d_in[1];
  const float* ilook = (const float*)d_in[2];
  const float* uW1   = (const float*)d_in[3];
  const float* ub1   = (const float*)d_in[4];
  const float* uW2   = (const float*)d_in[5];
  const float* ub2   = (const float*)d_in[6];
  const float* iW1   = (const float*)d_in[7];
  const float* ib1   = (const float*)d_in[8];
  const float* iW2   = (const float*)d_in[9];
  const float* ib2   = (const float*)d_in[10];
  float* out = (float*)d_out;

  // workspace layout (bytes):
  //   w1s: [2][272][512][8] bf16 = 4,456,448
  //   w2s: [2][64][256][8]  bf16 =   524,288  @ 4,456,448
  //   hsl: [2][8192*512]    bf16 = 16,777,216 @ 4,980,736
  char* ws = (char*)d_ws;
  unsigned short* w1s = (unsigned short*)(ws);
  unsigned short* w2s = (unsigned short*)(ws + 4456448);
  unsigned short* hsl = (unsigned short*)(ws + 4980736);

  ASAECF_tcast<<<dim3(544, 2, 2), 256, 0, stream>>>(uW1, iW1, uW2, iW2, w1s, w2s);
  ASAECF_gemm1<<<dim3(256), 512, 0, stream>>>(x, ulook, ilook, w1s, ub1, ib1, hsl);
  ASAECF_gemm2dot<<<dim3(256), 512, 0, stream>>>(hsl, w2s, ub2, ib2, out);
}